// Round 1
// baseline (10343.381 us; speedup 1.0000x reference)
//
#include <hip/hip_runtime.h>
#include <math.h>

// Problem constants
#define TT 16
#define BB 32
#define NN 256
#define DD 128
#define HH 16
#define NSTEPS 5
#define SKIPF 0.3f
#define EPSF 1e-8f

__device__ __forceinline__ float sigmoidf_(float x) {
    return 1.0f / (1.0f + __expf(-x));
}

// -------------------------------------------------------------------------
// K2: per-(h,b,n) inverse norms of xw = x * W_gl[h]
// grid = B*N blocks, 256 threads (4 waves x 4 heads each)
// -------------------------------------------------------------------------
__global__ __launch_bounds__(256) void k_norms(const float* __restrict__ x,
                                               const float* __restrict__ Wgl,
                                               float* __restrict__ invn) {
    int bid = blockIdx.x;            // 0..8191
    int b = bid >> 8, n = bid & 255;
    __shared__ float xr[128];
    int tid = threadIdx.x;
    if (tid < 128) xr[tid] = x[((b << 8) + n) * 128 + tid];
    __syncthreads();
    int wave = tid >> 6, lane = tid & 63;
    #pragma unroll
    for (int i = 0; i < 4; ++i) {
        int h = (wave << 2) + i;
        float v0 = xr[lane]      * Wgl[(h << 7) + lane];
        float v1 = xr[lane + 64] * Wgl[(h << 7) + lane + 64];
        float s = v0 * v0 + v1 * v1;
        #pragma unroll
        for (int off = 32; off; off >>= 1) s += __shfl_down(s, off, 64);
        if (lane == 0) invn[((h << 5) + b) * 256 + n] = 1.0f / (sqrtf(s) + EPSF);
    }
}

// -------------------------------------------------------------------------
// K3: att rows + relu + row-normalize + skip-connection A update (in place)
// grid = B * N/4 blocks (each block computes 4 adjacency rows), 256 threads
// att[b,n,m] = (1/H) sum_h invn[h,n]*invn[h,m]* sum_d x[n,d]*x[m,d]*Wgl[h,d]^2
// -------------------------------------------------------------------------
__global__ __launch_bounds__(256) void k_att(const float* __restrict__ x,
                                             const float* __restrict__ Wgl,
                                             const float* __restrict__ invn,
                                             float* __restrict__ A) {
    int bid = blockIdx.x;                 // 0..2047
    int b = bid >> 6;
    int n0 = (bid & 63) << 2;
    int tid = threadIdx.x;                // = m

    __shared__ float w2[16 * 128];        // 8KB
    __shared__ float xn4[4 * 128];        // 2KB
    __shared__ float xt[256 * 33];        // 33.8KB (stride-33 pad)
    __shared__ float invr[64];            // invn for the 4 target rows
    __shared__ float red[16];             // [k][wave]

    for (int i = tid; i < 2048; i += 256) { float w = Wgl[i]; w2[i] = w * w; }
    for (int i = tid; i < 512; i += 256) {
        int k = i >> 7, d = i & 127;
        xn4[i] = x[((b << 8) + n0 + k) * 128 + d];
    }
    if (tid < 64) {
        int h = tid >> 2, k = tid & 3;
        invr[tid] = invn[((h << 5) + b) * 256 + n0 + k];
    }
    __syncthreads();

    float acc[64];
    #pragma unroll
    for (int i = 0; i < 64; ++i) acc[i] = 0.0f;

    for (int dc = 0; dc < 4; ++dc) {
        // stage x[b, :, dc*32 : dc*32+32] -> xt
        for (int vi = tid; vi < 2048; vi += 256) {
            int m = vi >> 3, q = (vi & 7) << 2;
            const float4 v = *(const float4*)&x[((b << 8) + m) * 128 + (dc << 5) + q];
            float* dst = &xt[m * 33 + q];
            dst[0] = v.x; dst[1] = v.y; dst[2] = v.z; dst[3] = v.w;
        }
        __syncthreads();
        for (int dd = 0; dd < 32; ++dd) {
            int d = (dc << 5) + dd;
            float xm = xt[tid * 33 + dd];
            float p0 = xm * xn4[d];
            float p1 = xm * xn4[128 + d];
            float p2 = xm * xn4[256 + d];
            float p3 = xm * xn4[384 + d];
            #pragma unroll
            for (int h = 0; h < 16; ++h) {
                float w = w2[(h << 7) + d];
                acc[(h << 2) + 0] = fmaf(p0, w, acc[(h << 2) + 0]);
                acc[(h << 2) + 1] = fmaf(p1, w, acc[(h << 2) + 1]);
                acc[(h << 2) + 2] = fmaf(p2, w, acc[(h << 2) + 2]);
                acc[(h << 2) + 3] = fmaf(p3, w, acc[(h << 2) + 3]);
            }
        }
        __syncthreads();
    }

    // epilogue: scale by norms, mean over heads, relu, row-normalize, skip
    float invm[16];
    #pragma unroll
    for (int h = 0; h < 16; ++h) invm[h] = invn[((h << 5) + b) * 256 + tid];

    float att[4];
    #pragma unroll
    for (int k = 0; k < 4; ++k) {
        float s = 0.0f;
        #pragma unroll
        for (int h = 0; h < 16; ++h)
            s += acc[(h << 2) + k] * invr[(h << 2) + k] * invm[h];
        att[k] = fmaxf(s * 0.0625f, 0.0f);
    }

    int wave = tid >> 6, lane = tid & 63;
    #pragma unroll
    for (int k = 0; k < 4; ++k) {
        float s = att[k];
        #pragma unroll
        for (int off = 32; off; off >>= 1) s += __shfl_down(s, off, 64);
        if (lane == 0) red[(k << 2) + wave] = s;
    }
    __syncthreads();
    #pragma unroll
    for (int k = 0; k < 4; ++k) {
        float rs = red[(k << 2)] + red[(k << 2) + 1] + red[(k << 2) + 2] + red[(k << 2) + 3];
        float an = att[k] / (rs + EPSF);
        int idx = ((b << 8) + n0 + k) * 256 + tid;
        A[idx] = SKIPF * A[idx] + (1.0f - SKIPF) * an;
    }
}

// -------------------------------------------------------------------------
// G1: msg[b,n,:] = sum_m A[b,n,m] * h[b,m,:]
// grid = B*8 blocks (32 rows each), 256 threads: (g = tid>>6 row group, d0 = tid&63)
// -------------------------------------------------------------------------
__global__ __launch_bounds__(256) void k_msg(const float* __restrict__ A,
                                             const float* __restrict__ hin,
                                             float* __restrict__ msg) {
    int bid = blockIdx.x;           // 0..255
    int b = bid >> 3;
    int n0 = (bid & 7) << 5;
    int tid = threadIdx.x;
    int d0 = tid & 63;
    int d1 = d0 + 64;
    int g = tid >> 6;

    __shared__ __align__(16) float As[32 * 256];   // 32KB
    {
        const float* src = &A[((b << 8) + n0) * 256];
        for (int i = tid * 4; i < 8192; i += 1024)
            *(float4*)&As[i] = *(const float4*)&src[i];
    }
    __syncthreads();

    float acc0[8], acc1[8];
    #pragma unroll
    for (int k = 0; k < 8; ++k) { acc0[k] = 0.0f; acc1[k] = 0.0f; }

    const int bh = b << 15;  // b*256*128
    for (int m = 0; m < 256; m += 4) {
        float ha0 = hin[bh + (m + 0) * 128 + d0], hb0 = hin[bh + (m + 0) * 128 + d1];
        float ha1 = hin[bh + (m + 1) * 128 + d0], hb1 = hin[bh + (m + 1) * 128 + d1];
        float ha2 = hin[bh + (m + 2) * 128 + d0], hb2 = hin[bh + (m + 2) * 128 + d1];
        float ha3 = hin[bh + (m + 3) * 128 + d0], hb3 = hin[bh + (m + 3) * 128 + d1];
        #pragma unroll
        for (int k = 0; k < 8; ++k) {
            const float4 a4 = *(const float4*)&As[((g + (k << 2)) << 8) + m];
            acc0[k] = fmaf(a4.x, ha0, acc0[k]); acc1[k] = fmaf(a4.x, hb0, acc1[k]);
            acc0[k] = fmaf(a4.y, ha1, acc0[k]); acc1[k] = fmaf(a4.y, hb1, acc1[k]);
            acc0[k] = fmaf(a4.z, ha2, acc0[k]); acc1[k] = fmaf(a4.z, hb2, acc1[k]);
            acc0[k] = fmaf(a4.w, ha3, acc0[k]); acc1[k] = fmaf(a4.w, hb3, acc1[k]);
        }
    }
    #pragma unroll
    for (int k = 0; k < 8; ++k) {
        int n = n0 + g + (k << 2);
        msg[((b << 8) + n) * 128 + d0] = acc0[k];
        msg[((b << 8) + n) * 128 + d1] = acc1[k];
    }
}

// -------------------------------------------------------------------------
// Shared GEMM phase for the gate kernel: acc += S(32x128, LDS) @ W(128x128, global)
// thread covers columns d0 and d1 for 8 rows (g, g+4, ..., g+28)
// -------------------------------------------------------------------------
__device__ __forceinline__ void gemm_phase(const float* S, const float* __restrict__ W,
                                           int d0, int d1, int g,
                                           float acc0[8], float acc1[8]) {
    for (int e = 0; e < 128; e += 4) {
        float wa0 = W[(e + 0) * 128 + d0], wb0 = W[(e + 0) * 128 + d1];
        float wa1 = W[(e + 1) * 128 + d0], wb1 = W[(e + 1) * 128 + d1];
        float wa2 = W[(e + 2) * 128 + d0], wb2 = W[(e + 2) * 128 + d1];
        float wa3 = W[(e + 3) * 128 + d0], wb3 = W[(e + 3) * 128 + d1];
        #pragma unroll
        for (int k = 0; k < 8; ++k) {
            const float4 s4 = *(const float4*)&S[((g + (k << 2)) << 7) + e];
            acc0[k] = fmaf(s4.x, wa0, acc0[k]); acc1[k] = fmaf(s4.x, wb0, acc1[k]);
            acc0[k] = fmaf(s4.y, wa1, acc0[k]); acc1[k] = fmaf(s4.y, wb1, acc1[k]);
            acc0[k] = fmaf(s4.z, wa2, acc0[k]); acc1[k] = fmaf(s4.z, wb2, acc1[k]);
            acc0[k] = fmaf(s4.w, wa3, acc0[k]); acc1[k] = fmaf(s4.w, wb3, acc1[k]);
        }
    }
}

// -------------------------------------------------------------------------
// G2: fully-fused GRU gate step for a 32-row tile:
//   a = msg@Wa + ba ; r = sig([a,h]@Wr+br) ; z = sig([a,h]@Wz+bz)
//   h~ = tanh([a, r*h]@Wh + bh) ; h_out = (1-z)h + z h~
// grid = B*8 blocks, 256 threads
// -------------------------------------------------------------------------
__global__ __launch_bounds__(256) void k_gates(const float* __restrict__ msg,
                                               const float* __restrict__ hin,
                                               const float* __restrict__ Wa, const float* __restrict__ ba,
                                               const float* __restrict__ Wr, const float* __restrict__ br,
                                               const float* __restrict__ Wz, const float* __restrict__ bz,
                                               const float* __restrict__ Wh, const float* __restrict__ bh,
                                               float* __restrict__ hout) {
    int bid = blockIdx.x;
    int b = bid >> 3;
    int n0 = (bid & 7) << 5;
    int tid = threadIdx.x;
    int d0 = tid & 63;
    int d1 = d0 + 64;
    int g = tid >> 6;

    __shared__ __align__(16) float ms[32 * 128];
    __shared__ __align__(16) float hs[32 * 128];
    __shared__ __align__(16) float as_[32 * 128];
    __shared__ __align__(16) float rhs[32 * 128];

    {
        const int base = ((b << 8) + n0) * 128;
        for (int i = tid * 4; i < 4096; i += 1024) {
            *(float4*)&ms[i] = *(const float4*)&msg[base + i];
            *(float4*)&hs[i] = *(const float4*)&hin[base + i];
        }
    }
    __syncthreads();

    float acc0[8], acc1[8];

    // ---- phase a ----
    #pragma unroll
    for (int k = 0; k < 8; ++k) { acc0[k] = 0.0f; acc1[k] = 0.0f; }
    gemm_phase(ms, Wa, d0, d1, g, acc0, acc1);
    {
        float ba0 = ba[d0], ba1 = ba[d1];
        #pragma unroll
        for (int k = 0; k < 8; ++k) {
            int n = g + (k << 2);
            as_[(n << 7) + d0] = acc0[k] + ba0;
            as_[(n << 7) + d1] = acc1[k] + ba1;
        }
    }
    __syncthreads();

    // ---- phase r (and r*h) ----
    #pragma unroll
    for (int k = 0; k < 8; ++k) { acc0[k] = 0.0f; acc1[k] = 0.0f; }
    gemm_phase(as_, Wr, d0, d1, g, acc0, acc1);
    gemm_phase(hs, Wr + 16384, d0, d1, g, acc0, acc1);
    {
        float br0 = br[d0], br1 = br[d1];
        #pragma unroll
        for (int k = 0; k < 8; ++k) {
            int n = g + (k << 2);
            float r0 = sigmoidf_(acc0[k] + br0);
            float r1 = sigmoidf_(acc1[k] + br1);
            rhs[(n << 7) + d0] = r0 * hs[(n << 7) + d0];
            rhs[(n << 7) + d1] = r1 * hs[(n << 7) + d1];
        }
    }
    __syncthreads();

    // ---- phase z ----
    float z0[8], z1[8];
    #pragma unroll
    for (int k = 0; k < 8; ++k) { acc0[k] = 0.0f; acc1[k] = 0.0f; }
    gemm_phase(as_, Wz, d0, d1, g, acc0, acc1);
    gemm_phase(hs, Wz + 16384, d0, d1, g, acc0, acc1);
    {
        float bz0 = bz[d0], bz1 = bz[d1];
        #pragma unroll
        for (int k = 0; k < 8; ++k) {
            z0[k] = sigmoidf_(acc0[k] + bz0);
            z1[k] = sigmoidf_(acc1[k] + bz1);
        }
    }

    // ---- phase h_tilde + update ----
    #pragma unroll
    for (int k = 0; k < 8; ++k) { acc0[k] = 0.0f; acc1[k] = 0.0f; }
    gemm_phase(as_, Wh, d0, d1, g, acc0, acc1);
    gemm_phase(rhs, Wh + 16384, d0, d1, g, acc0, acc1);
    {
        float bh0 = bh[d0], bh1 = bh[d1];
        #pragma unroll
        for (int k = 0; k < 8; ++k) {
            int n = g + (k << 2);
            float ht0 = tanhf(acc0[k] + bh0);
            float ht1 = tanhf(acc1[k] + bh1);
            float hv0 = hs[(n << 7) + d0];
            float hv1 = hs[(n << 7) + d1];
            int gidx = ((b << 8) + n0 + n) * 128;
            hout[gidx + d0] = hv0 + z0[k] * (ht0 - hv0);
            hout[gidx + d1] = hv1 + z1[k] * (ht1 - hv1);
        }
    }
}

// -------------------------------------------------------------------------
// Final classifier: logits[b,c] = sum_i h[b,i] * Wfc[i,c] + bfc[c]
// grid = B blocks, 256 threads
// -------------------------------------------------------------------------
__global__ __launch_bounds__(256) void k_fc(const float* __restrict__ h,
                                            const float* __restrict__ Wfc,
                                            const float* __restrict__ bfc,
                                            float* __restrict__ out) {
    int b = blockIdx.x;
    int tid = threadIdx.x;
    float a0 = 0.0f, a1 = 0.0f;
    const float* hb = &h[b * 32768];
    for (int i = tid; i < 32768; i += 256) {
        float v = hb[i];
        const float2 w = *(const float2*)&Wfc[i * 2];
        a0 = fmaf(v, w.x, a0);
        a1 = fmaf(v, w.y, a1);
    }
    int wave = tid >> 6, lane = tid & 63;
    #pragma unroll
    for (int off = 32; off; off >>= 1) {
        a0 += __shfl_down(a0, off, 64);
        a1 += __shfl_down(a1, off, 64);
    }
    __shared__ float r0[4], r1[4];
    if (lane == 0) { r0[wave] = a0; r1[wave] = a1; }
    __syncthreads();
    if (tid == 0) {
        out[b * 2 + 0] = r0[0] + r0[1] + r0[2] + r0[3] + bfc[0];
        out[b * 2 + 1] = r1[0] + r1[1] + r1[2] + r1[3] + bfc[1];
    }
}

// -------------------------------------------------------------------------
extern "C" void kernel_launch(void* const* d_in, const int* in_sizes, int n_in,
                              void* d_out, int out_size, void* d_ws, size_t ws_size,
                              hipStream_t stream) {
    const float* x_all = (const float*)d_in[0];   // (T,B,N,D)
    const float* supports = (const float*)d_in[1];// (B,N,N)
    const float* Wgl = (const float*)d_in[2];     // (H,D)
    const float* Wa  = (const float*)d_in[3];
    const float* ba  = (const float*)d_in[4];
    const float* Wr  = (const float*)d_in[5];
    const float* br  = (const float*)d_in[6];
    const float* Wz  = (const float*)d_in[7];
    const float* bz  = (const float*)d_in[8];
    const float* Wh  = (const float*)d_in[9];
    const float* bh  = (const float*)d_in[10];
    const float* Wfc = (const float*)d_in[11];
    const float* bfc = (const float*)d_in[12];
    float* out = (float*)d_out;

    float* A    = (float*)d_ws;                       // B*N*N      = 2,097,152 f
    float* invn = A + (size_t)BB * NN * NN;           // H*B*N      =   131,072 f
    float* h0   = invn + (size_t)HH * BB * NN;        // B*N*D      = 1,048,576 f
    float* h1   = h0 + (size_t)BB * NN * DD;
    float* msg  = h1 + (size_t)BB * NN * DD;

    hipMemcpyAsync(A, supports, (size_t)BB * NN * NN * sizeof(float),
                   hipMemcpyDeviceToDevice, stream);

    for (int t = 0; t < TT; ++t) {
        const float* xt = x_all + (size_t)t * BB * NN * DD;
        k_norms<<<BB * NN, 256, 0, stream>>>(xt, Wgl, invn);
        k_att<<<BB * (NN / 4), 256, 0, stream>>>(xt, Wgl, invn, A);

        const float* hin = xt;
        float* cur = h0;
        float* alt = h1;
        for (int s = 0; s < NSTEPS; ++s) {
            k_msg<<<BB * 8, 256, 0, stream>>>(A, hin, msg);
            k_gates<<<BB * 8, 256, 0, stream>>>(msg, hin, Wa, ba, Wr, br, Wz, bz, Wh, bh, cur);
            hin = cur;
            float* tmp = cur; cur = alt; alt = tmp;
        }
        // after 5 steps the latest h lives in h0
    }

    k_fc<<<BB, 256, 0, stream>>>(h0, Wfc, bfc, out);
}

// Round 2
// 2901.362 us; speedup vs baseline: 3.5650x; 3.5650x over previous
//
#include <hip/hip_runtime.h>
#include <math.h>

#define TT 16
#define BB 32
#define NN 256
#define DD 128
#define HH 16
#define NSTEPS 5
#define SKIPF 0.3f
#define EPSF 1e-8f

typedef __attribute__((ext_vector_type(8))) short bf16x8;
typedef __attribute__((ext_vector_type(4))) float f32x4;

__device__ __forceinline__ unsigned short f2bf(float f) {
    union { float f; unsigned u; } v; v.f = f;
    unsigned r = (v.u + 0x7FFF + ((v.u >> 16) & 1)) >> 16;
    return (unsigned short)r;
}
__device__ __forceinline__ unsigned pack2(unsigned short a, unsigned short b) {
    return (unsigned)a | ((unsigned)b << 16);
}
__device__ __forceinline__ float sigmoidf_(float x) {
    return 1.0f / (1.0f + __expf(-x));
}

// ---------------------------------------------------------------------------
// buildV: V[b,n,h*128+d] = bf16( x[b,n,d]*Wgl[h,d] / (||x*w_h|| + eps) )
// grid = B*N (8192) blocks x 128 threads
// ---------------------------------------------------------------------------
__global__ __launch_bounds__(128) void k_buildV(const float* __restrict__ x,
                                                const float* __restrict__ Wgl,
                                                unsigned short* __restrict__ V) {
    int bid = blockIdx.x;
    int b = bid >> 8, n = bid & 255;
    int d = threadIdx.x;
    __shared__ float part[16][2];
    float xv = x[(((b << 8) + n) << 7) + d];
    float vv[16];
    int wave = d >> 6, lane = d & 63;
    #pragma unroll
    for (int h = 0; h < 16; ++h) {
        float v = xv * Wgl[(h << 7) + d];
        vv[h] = v;
        float s = v * v;
        #pragma unroll
        for (int off = 32; off; off >>= 1) s += __shfl_down(s, off, 64);
        if (lane == 0) part[h][wave] = s;
    }
    __syncthreads();
    unsigned short* Vr = V + ((size_t)((b << 8) + n) << 11);
    #pragma unroll
    for (int h = 0; h < 16; ++h) {
        float inv = 1.0f / (sqrtf(part[h][0] + part[h][1]) + EPSF);
        Vr[(h << 7) + d] = f2bf(vv[h] * inv);
    }
}

// ---------------------------------------------------------------------------
// xT: xT[b][d][n] = bf16(x[b][n][d]);  grid = 32*4*8 = 1024 blocks x 256 thr
// ---------------------------------------------------------------------------
__global__ __launch_bounds__(256) void k_xT(const float* __restrict__ x,
                                            unsigned short* __restrict__ xT) {
    int bid = blockIdx.x;
    int b = bid >> 5; int r = bid & 31; int d0 = (r >> 3) << 5; int n0 = (r & 7) << 5;
    __shared__ float t[32][33];
    int tid = threadIdx.x;
    int i = tid >> 5, j = tid & 31;
    #pragma unroll
    for (int s = 0; s < 4; ++s) {
        int nl = (s << 3) + i;
        t[nl][j] = x[(((b << 8) + n0 + nl) << 7) + d0 + j];
    }
    __syncthreads();
    #pragma unroll
    for (int s = 0; s < 4; ++s) {
        int dd = (s << 3) + i;
        xT[(((b << 7) + d0 + dd) << 8) + n0 + j] = f2bf(t[j][dd]);
    }
}

// ---------------------------------------------------------------------------
// wprep: bf16-transposed weights WT[dout][k]
// grid = 128 blocks x 256 threads (32768 threads)
// ---------------------------------------------------------------------------
__global__ __launch_bounds__(256) void k_wprep(const float* __restrict__ Wa,
                                               const float* __restrict__ Wr,
                                               const float* __restrict__ Wz,
                                               const float* __restrict__ Wh,
                                               unsigned short* __restrict__ WaT,
                                               unsigned short* __restrict__ WrT,
                                               unsigned short* __restrict__ WzT,
                                               unsigned short* __restrict__ WhT) {
    int idx = blockIdx.x * 256 + threadIdx.x;     // 0..32767
    if (idx < 16384) {
        int dout = idx >> 7, din = idx & 127;
        WaT[idx] = f2bf(Wa[(din << 7) + dout]);
    }
    {
        int dout = idx >> 8, dk = idx & 255;
        WrT[idx] = f2bf(Wr[(dk << 7) + dout]);
        WzT[idx] = f2bf(Wz[(dk << 7) + dout]);
        WhT[idx] = f2bf(Wh[(dk << 7) + dout]);
    }
}

// ---------------------------------------------------------------------------
// att2: per b, att = relu(V V^T) row-normalized; A = 0.3A + 0.7 att (f32+bf16)
// grid = 256 blocks (b = bid&31, rg = bid>>5 -> 32 rows), 256 threads
// ---------------------------------------------------------------------------
__global__ __launch_bounds__(256) void k_att2(const unsigned short* __restrict__ V,
                                              float* __restrict__ A,
                                              unsigned short* __restrict__ Abf) {
    int bid = blockIdx.x;
    int b = bid & 31, rg = bid >> 5;
    int n0 = rg << 5;
    int tid = threadIdx.x;
    int wave = tid >> 6, lane = tid & 63;
    int m16 = lane & 15, quad = lane >> 4;

    __shared__ unsigned short Vs[256 * 72];   // 256 rows x 64k chunk, pad->72
    __shared__ float rsum[4][32];

    f32x4 acc[2][4];
    #pragma unroll
    for (int rb = 0; rb < 2; ++rb)
        #pragma unroll
        for (int cb = 0; cb < 4; ++cb) acc[rb][cb] = (f32x4){0.f, 0.f, 0.f, 0.f};

    const unsigned short* Vb = V + ((size_t)b << 19);  // b*256*2048

    for (int kc = 0; kc < 2048; kc += 64) {
        __syncthreads();
        {
            const unsigned short* src = Vb + ((size_t)tid << 11) + kc;
            unsigned short* dst = Vs + tid * 72;
            #pragma unroll
            for (int i = 0; i < 8; ++i)
                *(int4*)(dst + (i << 3)) = *(const int4*)(src + (i << 3));
        }
        __syncthreads();
        #pragma unroll
        for (int ks = 0; ks < 2; ++ks) {
            bf16x8 afr[2], bfr[4];
            #pragma unroll
            for (int rb = 0; rb < 2; ++rb)
                afr[rb] = *(const bf16x8*)(Vs + (n0 + (rb << 4) + m16) * 72 + (ks << 5) + (quad << 3));
            #pragma unroll
            for (int cb = 0; cb < 4; ++cb)
                bfr[cb] = *(const bf16x8*)(Vs + ((wave << 6) + (cb << 4) + m16) * 72 + (ks << 5) + (quad << 3));
            #pragma unroll
            for (int rb = 0; rb < 2; ++rb)
                #pragma unroll
                for (int cb = 0; cb < 4; ++cb)
                    acc[rb][cb] = __builtin_amdgcn_mfma_f32_16x16x32_bf16(afr[rb], bfr[cb], acc[rb][cb], 0, 0, 0);
        }
    }

    // relu + per-row partial sums over this wave's 64 cols
    float rs[2][4];
    #pragma unroll
    for (int rb = 0; rb < 2; ++rb)
        #pragma unroll
        for (int r = 0; r < 4; ++r) {
            float s = 0.f;
            #pragma unroll
            for (int cb = 0; cb < 4; ++cb) {
                float v = fmaxf(acc[rb][cb][r], 0.0f);
                acc[rb][cb][r] = v;
                s += v;
            }
            rs[rb][r] = s;
        }
    #pragma unroll
    for (int m = 1; m < 16; m <<= 1)
        #pragma unroll
        for (int rb = 0; rb < 2; ++rb)
            #pragma unroll
            for (int r = 0; r < 4; ++r)
                rs[rb][r] += __shfl_xor(rs[rb][r], m, 64);
    if (m16 == 0) {
        #pragma unroll
        for (int rb = 0; rb < 2; ++rb)
            #pragma unroll
            for (int r = 0; r < 4; ++r)
                rsum[wave][(rb << 4) + (quad << 2) + r] = rs[rb][r];
    }
    __syncthreads();

    #pragma unroll
    for (int rb = 0; rb < 2; ++rb) {
        #pragma unroll
        for (int r = 0; r < 4; ++r) {
            int row = (rb << 4) + (quad << 2) + r;
            float tot = rsum[0][row] + rsum[1][row] + rsum[2][row] + rsum[3][row];
            float inv = (1.0f - SKIPF) / (tot + 16.0f * EPSF);
            size_t base = ((size_t)((b << 8) + n0 + row)) << 8;
            #pragma unroll
            for (int cb = 0; cb < 4; ++cb) {
                int col = (wave << 6) + (cb << 4) + m16;
                size_t idx = base + col;
                float an = SKIPF * A[idx] + acc[rb][cb][r] * inv;
                A[idx] = an;
                Abf[idx] = f2bf(an);
            }
        }
    }
}

// ---------------------------------------------------------------------------
// step: fused GGNN/GRU step for 32 rows. grid = 256 blocks x 256 threads.
//   msg = A_tile @ h  (K=256, B-op from hT)
//   a   = msg @ Wa + ba
//   r,z = sig([a|h] @ W{r,z} + b)    (A-op = ahS LDS, B-op direct global WT)
//   h~  = tanh([a|r*h] @ Wh + bh)
//   h'  = h + z*(h~ - h)             (f32)
// ---------------------------------------------------------------------------
__global__ __launch_bounds__(256) void k_step(
    const unsigned short* __restrict__ Abf,
    const unsigned short* __restrict__ hT,
    const float* __restrict__ hf,
    const unsigned short* __restrict__ WaT, const float* __restrict__ ba,
    const unsigned short* __restrict__ WrT, const float* __restrict__ br,
    const unsigned short* __restrict__ WzT, const float* __restrict__ bz,
    const unsigned short* __restrict__ WhT, const float* __restrict__ bh,
    float* __restrict__ hf_o, unsigned short* __restrict__ hT_o) {

    int bid = blockIdx.x;
    int b = bid & 31, rg = bid >> 5;
    int n0 = rg << 5;
    int tid = threadIdx.x;
    int wave = tid >> 6, lane = tid & 63;
    int m16 = lane & 15, quad = lane >> 4;
    int wcol = wave << 5;

    __shared__ unsigned short msgS[32 * 136];
    __shared__ unsigned short ahS[32 * 264];   // k 0..127 = a, 128..255 = h (later r*h)

    // stage h-half of ahS (f32 -> bf16)
    #pragma unroll
    for (int s = 0; s < 2; ++s) {
        int task = tid + (s << 8);
        int row = task >> 4, ch = (task & 15) << 3;
        const float* src = hf + (((size_t)((b << 8) + n0 + row)) << 7) + ch;
        unsigned short t0[8];
        #pragma unroll
        for (int i = 0; i < 8; ++i) t0[i] = f2bf(src[i]);
        uint4 o;
        o.x = pack2(t0[0], t0[1]); o.y = pack2(t0[2], t0[3]);
        o.z = pack2(t0[4], t0[5]); o.w = pack2(t0[6], t0[7]);
        *(uint4*)(ahS + row * 264 + 128 + ch) = o;
    }

    // ---- bmm: msg = A_tile @ h ----
    f32x4 acc[2][2];
    #pragma unroll
    for (int rb = 0; rb < 2; ++rb)
        #pragma unroll
        for (int cb = 0; cb < 2; ++cb) acc[rb][cb] = (f32x4){0.f, 0.f, 0.f, 0.f};

    const unsigned short* Ab = Abf + ((size_t)b << 16) + ((size_t)n0 << 8);
    const unsigned short* hTb = hT + ((size_t)b << 15);
    #pragma unroll 2
    for (int ks = 0; ks < 8; ++ks) {
        bf16x8 af[2], bf[2];
        #pragma unroll
        for (int rb = 0; rb < 2; ++rb)
            af[rb] = *(const bf16x8*)(Ab + (((rb << 4) + m16) << 8) + (ks << 5) + (quad << 3));
        #pragma unroll
        for (int cb = 0; cb < 2; ++cb)
            bf[cb] = *(const bf16x8*)(hTb + ((wcol + (cb << 4) + m16) << 8) + (ks << 5) + (quad << 3));
        #pragma unroll
        for (int rb = 0; rb < 2; ++rb)
            #pragma unroll
            for (int cb = 0; cb < 2; ++cb)
                acc[rb][cb] = __builtin_amdgcn_mfma_f32_16x16x32_bf16(af[rb], bf[cb], acc[rb][cb], 0, 0, 0);
    }
    #pragma unroll
    for (int rb = 0; rb < 2; ++rb)
        #pragma unroll
        for (int cb = 0; cb < 2; ++cb)
            #pragma unroll
            for (int r = 0; r < 4; ++r)
                msgS[((rb << 4) + (quad << 2) + r) * 136 + wcol + (cb << 4) + m16] = f2bf(acc[rb][cb][r]);
    __syncthreads();

    // ---- a = msg @ Wa + ba ----
    #pragma unroll
    for (int rb = 0; rb < 2; ++rb)
        #pragma unroll
        for (int cb = 0; cb < 2; ++cb) acc[rb][cb] = (f32x4){0.f, 0.f, 0.f, 0.f};
    #pragma unroll
    for (int ks = 0; ks < 4; ++ks) {
        bf16x8 af[2], bf[2];
        #pragma unroll
        for (int rb = 0; rb < 2; ++rb)
            af[rb] = *(const bf16x8*)(msgS + ((rb << 4) + m16) * 136 + (ks << 5) + (quad << 3));
        #pragma unroll
        for (int cb = 0; cb < 2; ++cb)
            bf[cb] = *(const bf16x8*)(WaT + ((wcol + (cb << 4) + m16) << 7) + (ks << 5) + (quad << 3));
        #pragma unroll
        for (int rb = 0; rb < 2; ++rb)
            #pragma unroll
            for (int cb = 0; cb < 2; ++cb)
                acc[rb][cb] = __builtin_amdgcn_mfma_f32_16x16x32_bf16(af[rb], bf[cb], acc[rb][cb], 0, 0, 0);
    }
    {
        float bav[2];
        #pragma unroll
        for (int cb = 0; cb < 2; ++cb) bav[cb] = ba[wcol + (cb << 4) + m16];
        #pragma unroll
        for (int rb = 0; rb < 2; ++rb)
            #pragma unroll
            for (int cb = 0; cb < 2; ++cb)
                #pragma unroll
                for (int r = 0; r < 4; ++r)
                    ahS[((rb << 4) + (quad << 2) + r) * 264 + wcol + (cb << 4) + m16] =
                        f2bf(acc[rb][cb][r] + bav[cb]);
    }
    __syncthreads();

    // h_old f32 loads (needed for r*h and final update)
    float hv[2][2][4];
    #pragma unroll
    for (int rb = 0; rb < 2; ++rb)
        #pragma unroll
        for (int cb = 0; cb < 2; ++cb)
            #pragma unroll
            for (int r = 0; r < 4; ++r)
                hv[rb][cb][r] = hf[(((size_t)((b << 8) + n0 + (rb << 4) + (quad << 2) + r)) << 7)
                                  + wcol + (cb << 4) + m16];

    // ---- r and z ----
    f32x4 racc[2][2], zacc[2][2];
    #pragma unroll
    for (int rb = 0; rb < 2; ++rb)
        #pragma unroll
        for (int cb = 0; cb < 2; ++cb) {
            racc[rb][cb] = (f32x4){0.f, 0.f, 0.f, 0.f};
            zacc[rb][cb] = (f32x4){0.f, 0.f, 0.f, 0.f};
        }
    #pragma unroll 2
    for (int ks = 0; ks < 8; ++ks) {
        bf16x8 af[2], bfr[2], bfz[2];
        #pragma unroll
        for (int rb = 0; rb < 2; ++rb)
            af[rb] = *(const bf16x8*)(ahS + ((rb << 4) + m16) * 264 + (ks << 5) + (quad << 3));
        #pragma unroll
        for (int cb = 0; cb < 2; ++cb) {
            int dout = wcol + (cb << 4) + m16;
            bfr[cb] = *(const bf16x8*)(WrT + (dout << 8) + (ks << 5) + (quad << 3));
            bfz[cb] = *(const bf16x8*)(WzT + (dout << 8) + (ks << 5) + (quad << 3));
        }
        #pragma unroll
        for (int rb = 0; rb < 2; ++rb)
            #pragma unroll
            for (int cb = 0; cb < 2; ++cb) {
                racc[rb][cb] = __builtin_amdgcn_mfma_f32_16x16x32_bf16(af[rb], bfr[cb], racc[rb][cb], 0, 0, 0);
                zacc[rb][cb] = __builtin_amdgcn_mfma_f32_16x16x32_bf16(af[rb], bfz[cb], zacc[rb][cb], 0, 0, 0);
            }
    }
    float zv[2][2][4];
    {
        float brv[2], bzv[2];
        #pragma unroll
        for (int cb = 0; cb < 2; ++cb) {
            brv[cb] = br[wcol + (cb << 4) + m16];
            bzv[cb] = bz[wcol + (cb << 4) + m16];
        }
        #pragma unroll
        for (int rb = 0; rb < 2; ++rb)
            #pragma unroll
            for (int cb = 0; cb < 2; ++cb)
                #pragma unroll
                for (int r = 0; r < 4; ++r) {
                    racc[rb][cb][r] = sigmoidf_(racc[rb][cb][r] + brv[cb]);
                    zv[rb][cb][r]  = sigmoidf_(zacc[rb][cb][r] + bzv[cb]);
                }
    }
    __syncthreads();   // all ahS reads done -> safe to overwrite h-half

    #pragma unroll
    for (int rb = 0; rb < 2; ++rb)
        #pragma unroll
        for (int cb = 0; cb < 2; ++cb)
            #pragma unroll
            for (int r = 0; r < 4; ++r)
                ahS[((rb << 4) + (quad << 2) + r) * 264 + 128 + wcol + (cb << 4) + m16] =
                    f2bf(racc[rb][cb][r] * hv[rb][cb][r]);
    __syncthreads();

    // ---- h_tilde ----
    #pragma unroll
    for (int rb = 0; rb < 2; ++rb)
        #pragma unroll
        for (int cb = 0; cb < 2; ++cb) acc[rb][cb] = (f32x4){0.f, 0.f, 0.f, 0.f};
    #pragma unroll 2
    for (int ks = 0; ks < 8; ++ks) {
        bf16x8 af[2], bf[2];
        #pragma unroll
        for (int rb = 0; rb < 2; ++rb)
            af[rb] = *(const bf16x8*)(ahS + ((rb << 4) + m16) * 264 + (ks << 5) + (quad << 3));
        #pragma unroll
        for (int cb = 0; cb < 2; ++cb)
            bf[cb] = *(const bf16x8*)(WhT + ((wcol + (cb << 4) + m16) << 8) + (ks << 5) + (quad << 3));
        #pragma unroll
        for (int rb = 0; rb < 2; ++rb)
            #pragma unroll
            for (int cb = 0; cb < 2; ++cb)
                acc[rb][cb] = __builtin_amdgcn_mfma_f32_16x16x32_bf16(af[rb], bf[cb], acc[rb][cb], 0, 0, 0);
    }

    // ---- update + writes ----
    {
        float bhv[2];
        #pragma unroll
        for (int cb = 0; cb < 2; ++cb) bhv[cb] = bh[wcol + (cb << 4) + m16];
        #pragma unroll
        for (int rb = 0; rb < 2; ++rb)
            #pragma unroll
            for (int cb = 0; cb < 2; ++cb) {
                int col = wcol + (cb << 4) + m16;
                unsigned short pk[4];
                #pragma unroll
                for (int r = 0; r < 4; ++r) {
                    float ht = tanhf(acc[rb][cb][r] + bhv[cb]);
                    float hn = hv[rb][cb][r] + zv[rb][cb][r] * (ht - hv[rb][cb][r]);
                    int row = n0 + (rb << 4) + (quad << 2) + r;
                    hf_o[(((size_t)((b << 8) + row)) << 7) + col] = hn;
                    pk[r] = f2bf(hn);
                }
                uint2 p;
                p.x = pack2(pk[0], pk[1]); p.y = pack2(pk[2], pk[3]);
                *(uint2*)(hT_o + (((size_t)((b << 7) + col)) << 8) + n0 + (rb << 4) + (quad << 2)) = p;
            }
    }
}

// ---------------------------------------------------------------------------
__global__ __launch_bounds__(256) void k_fc(const float* __restrict__ h,
                                            const float* __restrict__ Wfc,
                                            const float* __restrict__ bfc,
                                            float* __restrict__ out) {
    int b = blockIdx.x;
    int tid = threadIdx.x;
    float a0 = 0.0f, a1 = 0.0f;
    const float* hb = &h[b * 32768];
    for (int i = tid; i < 32768; i += 256) {
        float v = hb[i];
        const float2 w = *(const float2*)&Wfc[i * 2];
        a0 = fmaf(v, w.x, a0);
        a1 = fmaf(v, w.y, a1);
    }
    int wave = tid >> 6, lane = tid & 63;
    #pragma unroll
    for (int off = 32; off; off >>= 1) {
        a0 += __shfl_down(a0, off, 64);
        a1 += __shfl_down(a1, off, 64);
    }
    __shared__ float r0[4], r1[4];
    if (lane == 0) { r0[wave] = a0; r1[wave] = a1; }
    __syncthreads();
    if (tid == 0) {
        out[b * 2 + 0] = r0[0] + r0[1] + r0[2] + r0[3] + bfc[0];
        out[b * 2 + 1] = r1[0] + r1[1] + r1[2] + r1[3] + bfc[1];
    }
}

// ---------------------------------------------------------------------------
extern "C" void kernel_launch(void* const* d_in, const int* in_sizes, int n_in,
                              void* d_out, int out_size, void* d_ws, size_t ws_size,
                              hipStream_t stream) {
    const float* x_all    = (const float*)d_in[0];
    const float* supports = (const float*)d_in[1];
    const float* Wgl = (const float*)d_in[2];
    const float* Wa  = (const float*)d_in[3];
    const float* ba  = (const float*)d_in[4];
    const float* Wr  = (const float*)d_in[5];
    const float* br  = (const float*)d_in[6];
    const float* Wz  = (const float*)d_in[7];
    const float* bz  = (const float*)d_in[8];
    const float* Wh  = (const float*)d_in[9];
    const float* bh  = (const float*)d_in[10];
    const float* Wfc = (const float*)d_in[11];
    const float* bfc = (const float*)d_in[12];
    float* out = (float*)d_out;

    char* p = (char*)d_ws;
    auto alloc = [&](size_t bytes) { char* r = p; p += (bytes + 255) & ~(size_t)255; return r; };

    float* A            = (float*)alloc((size_t)BB * NN * NN * 4);          // 8 MB
    unsigned short* V   = (unsigned short*)alloc((size_t)BB * NN * 2048 * 2); // 32 MB
    unsigned short* Abf = (unsigned short*)alloc((size_t)BB * NN * NN * 2);  // 4 MB
    unsigned short* xT  = (unsigned short*)alloc((size_t)BB * DD * NN * 2);  // 2 MB
    float* hf0          = (float*)alloc((size_t)BB * NN * DD * 4);           // 4 MB
    float* hf1          = (float*)alloc((size_t)BB * NN * DD * 4);
    unsigned short* hT0 = (unsigned short*)alloc((size_t)BB * DD * NN * 2);
    unsigned short* hT1 = (unsigned short*)alloc((size_t)BB * DD * NN * 2);
    unsigned short* WaT = (unsigned short*)alloc(128 * 128 * 2);
    unsigned short* WrT = (unsigned short*)alloc(256 * 128 * 2);
    unsigned short* WzT = (unsigned short*)alloc(256 * 128 * 2);
    unsigned short* WhT = (unsigned short*)alloc(256 * 128 * 2);

    hipMemcpyAsync(A, supports, (size_t)BB * NN * NN * sizeof(float),
                   hipMemcpyDeviceToDevice, stream);
    k_wprep<<<128, 256, 0, stream>>>(Wa, Wr, Wz, Wh, WaT, WrT, WzT, WhT);

    for (int t = 0; t < TT; ++t) {
        const float* xt = x_all + (size_t)t * BB * NN * DD;
        k_buildV<<<BB * NN, 128, 0, stream>>>(xt, Wgl, V);
        k_xT<<<BB * 32, 256, 0, stream>>>(xt, xT);
        k_att2<<<256, 256, 0, stream>>>(V, A, Abf);

        const unsigned short* hT_in = xT;
        const float* hf_in = xt;
        for (int s = 0; s < NSTEPS; ++s) {
            float* hf_out = (s & 1) ? hf1 : hf0;
            unsigned short* hT_out = (s & 1) ? hT1 : hT0;
            k_step<<<256, 256, 0, stream>>>(Abf, hT_in, hf_in,
                                            WaT, ba, WrT, br, WzT, bz, WhT, bh,
                                            hf_out, hT_out);
            hf_in = hf_out;
            hT_in = hT_out;
        }
    }
    k_fc<<<BB, 256, 0, stream>>>(hf0, Wfc, bfc, out);
}